// Round 1
// baseline (3844.628 us; speedup 1.0000x reference)
//
#include <hip/hip_runtime.h>

typedef __bf16 bf16_t;
typedef __bf16 bf16x8 __attribute__((ext_vector_type(8)));
typedef float f32x4 __attribute__((ext_vector_type(4)));

#define EPSBN 1e-5f

__device__ __forceinline__ void gload16(const void* g, void* l) {
  __builtin_amdgcn_global_load_lds(
      (const __attribute__((address_space(1))) void*)g,
      (__attribute__((address_space(3))) void*)l, 16, 0, 0);
}

// ---------------- weight packing: fp32 -> bf16 (w1 padded 20->32 ch) ----------------
__global__ __launch_bounds__(256) void pack_w_kernel(
    const float* __restrict__ w1, const float* __restrict__ w2,
    const float* __restrict__ w3, const float* __restrict__ w4,
    const float* __restrict__ w5,
    bf16_t* __restrict__ p1, bf16_t* __restrict__ p2, bf16_t* __restrict__ p3,
    bf16_t* __restrict__ p4, bf16_t* __restrict__ p5)
{
  const int idx = blockIdx.x * 256 + threadIdx.x;
  switch (blockIdx.y) {
    case 0:
      if (idx < 256 * 160) {
        int o = idx / 160, k = idx % 160, tap = k / 32, ch = k % 32;
        p1[idx] = (bf16_t)((ch < 20) ? w1[o * 100 + tap * 20 + ch] : 0.0f);
      }
      break;
    case 1: if (idx < 512 * 1280) p2[idx] = (bf16_t)w2[idx]; break;
    case 2: if (idx < 256 * 2560) p3[idx] = (bf16_t)w3[idx]; break;
    case 3: if (idx < 128 * 768)  p4[idx] = (bf16_t)w4[idx]; break;
    default: if (idx < 128 * 384) p5[idx] = (bf16_t)w5[idx]; break;
  }
}

// ---------------- x: (B,20,L) fp32 -> (B,L,32) bf16, zero-padded channels ----------------
__global__ __launch_bounds__(256) void pack_x_kernel(
    const float* __restrict__ x, bf16_t* __restrict__ xp)
{
  __shared__ __align__(16) bf16_t Ls[256 * 32];
  const int tid = threadIdx.x;
  const int b = blockIdx.y;
  const int l0 = blockIdx.x * 256;
  bf16x8 z = {};
  #pragma unroll
  for (int i = 0; i < 4; ++i) ((bf16x8*)Ls)[tid + i * 256] = z;
  __syncthreads();
  #pragma unroll
  for (int ch = 0; ch < 20; ++ch) {
    float v = x[((size_t)b * 20 + ch) * 4096 + l0 + tid];
    Ls[tid * 32 + ch] = (bf16_t)v;
  }
  __syncthreads();
  bf16x8* dst = (bf16x8*)(xp + ((size_t)b * 4096 + l0) * 32);
  #pragma unroll
  for (int i = 0; i < 4; ++i) dst[tid + i * 256] = ((bf16x8*)Ls)[tid + i * 256];
}

// ---------------- TDNN layer as MFMA GEMM over dilated taps ----------------
// X: (B, Lin, DIN) bf16 ; W: (N, C*DIN) bf16 ; Y: (B, Lo, N)
// out = relu(f@w + bias) * (g*rsqrt(v+eps)) + (bb - m*g*rsqrt(v+eps))
template <int DIN, int C, int DIL, bool OUTF32>
__global__ __launch_bounds__(256, 2) void tdnn_gemm(
    const bf16_t* __restrict__ X, const bf16_t* __restrict__ W,
    const float* __restrict__ bias, const float* __restrict__ gg,
    const float* __restrict__ bb, const float* __restrict__ mm,
    const float* __restrict__ vv,
    bf16_t* __restrict__ Yb, float* __restrict__ Yf,
    const int Lin, const int Lo, const int N)
{
  __shared__ __align__(16) bf16_t As[128 * 32];
  __shared__ __align__(16) bf16_t Bs[128 * 32];
  const int tid = threadIdx.x;
  const int wave = tid >> 6;
  const int lane = tid & 63;
  const int l0 = blockIdx.x * 128;
  const int n0 = blockIdx.y * 128;
  const int b = blockIdx.z;
  const int lm = lane & 15;
  const int quad = lane >> 4;
  const int wm = (wave >> 1) * 64;   // wave's 64-row quadrant
  const int wn = (wave & 1) * 64;    // wave's 64-col quadrant
  constexpr int Ktot = C * DIN;

  // staging: each wave fills 32 rows of As and Bs (two 16-row dwordx4 calls)
  const int srow = wave * 32 + (lane >> 2);
  const int scol = (lane & 3) * 8;

  const int rA0 = min(l0 + srow, Lo - 1);        // clamp: rows >= Lo are garbage, never stored
  const int rA1 = min(l0 + srow + 16, Lo - 1);

  const bf16_t* Xb = X + (size_t)b * Lin * DIN;
  const bf16_t* xg0 = Xb + (size_t)rA0 * DIN + scol;
  const bf16_t* xg1 = Xb + (size_t)rA1 * DIN + scol;
  const bf16_t* wg0 = W + (size_t)(n0 + srow) * Ktot + scol;
  const bf16_t* wg1 = W + (size_t)(n0 + srow + 16) * Ktot + scol;

  bf16_t* AsW = &As[(wave * 32) * 32];
  bf16_t* BsW = &Bs[(wave * 32) * 32];

  f32x4 acc[4][4];
  f32x4 zz = {};
  #pragma unroll
  for (int i = 0; i < 4; ++i)
    #pragma unroll
    for (int j = 0; j < 4; ++j) acc[i][j] = zz;

  for (int tap = 0; tap < C; ++tap) {
    const bf16_t* xa0 = xg0 + (size_t)tap * DIL * DIN;
    const bf16_t* xa1 = xg1 + (size_t)tap * DIL * DIN;
    const bf16_t* wa0 = wg0 + tap * DIN;
    const bf16_t* wa1 = wg1 + tap * DIN;
    for (int kc = 0; kc < DIN / 32; ++kc) {
      gload16(xa0 + kc * 32, AsW);
      gload16(xa1 + kc * 32, AsW + 16 * 32);
      gload16(wa0 + kc * 32, BsW);
      gload16(wa1 + kc * 32, BsW + 16 * 32);
      __syncthreads();
      bf16x8 av[4], bv[4];
      #pragma unroll
      for (int mt = 0; mt < 4; ++mt)
        av[mt] = *(const bf16x8*)&As[(wm + mt * 16 + lm) * 32 + quad * 8];
      #pragma unroll
      for (int nt = 0; nt < 4; ++nt)
        bv[nt] = *(const bf16x8*)&Bs[(wn + nt * 16 + lm) * 32 + quad * 8];
      #pragma unroll
      for (int mt = 0; mt < 4; ++mt)
        #pragma unroll
        for (int nt = 0; nt < 4; ++nt)
          acc[mt][nt] = __builtin_amdgcn_mfma_f32_16x16x32_bf16(av[mt], bv[nt], acc[mt][nt], 0, 0, 0);
      __syncthreads();
    }
  }

  // epilogue: bias + relu + BN(eval), C/D layout col=lane&15, row=quad*4+reg
  #pragma unroll
  for (int nt = 0; nt < 4; ++nt) {
    const int col = n0 + wn + nt * 16 + lm;
    const float sc = gg[col] * rsqrtf(vv[col] + EPSBN);
    const float sh = bb[col] - mm[col] * sc;
    const float bi = bias[col];
    #pragma unroll
    for (int mt = 0; mt < 4; ++mt) {
      const int rbase = l0 + wm + mt * 16 + quad * 4;
      #pragma unroll
      for (int r = 0; r < 4; ++r) {
        const int row = rbase + r;
        if (row < Lo) {
          float val = fmaxf(acc[mt][nt][r] + bi, 0.0f) * sc + sh;
          const size_t oi = ((size_t)b * Lo + row) * N + col;
          if constexpr (OUTF32) Yf[oi] = val;
          else                  Yb[oi] = (bf16_t)val;
        }
      }
    }
  }
}

// ---------------- gi0 = act5 @ wih0^T + bih0, fp32 (keeps recurrent path accurate) ----------------
__global__ __launch_bounds__(256, 2) void gi0_kernel(
    const float* __restrict__ A5, const float* __restrict__ wih,
    const float* __restrict__ bih, float* __restrict__ GI, const int T)
{
  __shared__ __align__(16) float Xs[64 * 132];
  __shared__ __align__(16) float Ws[48 * 132];
  const int tid = threadIdx.x;
  const int b = blockIdx.y, t0 = blockIdx.x * 64;
  for (int c = tid; c < 48 * 32; c += 256) {
    int j = c >> 5, k4 = c & 31;
    *(float4*)&Ws[j * 132 + k4 * 4] = *(const float4*)&wih[j * 128 + k4 * 4];
  }
  for (int c = tid; c < 64 * 32; c += 256) {
    int r = c >> 5, k4 = c & 31;
    int tt = min(t0 + r, T - 1);
    *(float4*)&Xs[r * 132 + k4 * 4] = *(const float4*)&A5[((size_t)b * T + tt) * 128 + k4 * 4];
  }
  __syncthreads();
  const int tl = tid >> 2, jg = tid & 3;
  float acc[12];
  #pragma unroll
  for (int i = 0; i < 12; ++i) acc[i] = 0.0f;
  for (int k = 0; k < 128; k += 4) {
    float4 xv = *(const float4*)&Xs[tl * 132 + k];
    #pragma unroll
    for (int jj = 0; jj < 12; ++jj) {
      float4 wv = *(const float4*)&Ws[(jg * 12 + jj) * 132 + k];
      acc[jj] += xv.x * wv.x + xv.y * wv.y + xv.z * wv.z + xv.w * wv.w;
    }
  }
  const int t = t0 + tl;
  if (t < T) {
    float* dst = &GI[((size_t)b * T + t) * 48 + jg * 12];
    #pragma unroll
    for (int jj = 0; jj < 12; ++jj) dst[jj] = acc[jj] + bih[jg * 12 + jj];
  }
}

// ---------------- fused 2-layer GRU scan: one wave per batch ----------------
__global__ __launch_bounds__(64, 1) void gru_kernel(
    const float* __restrict__ GI,
    const float* __restrict__ whh0, const float* __restrict__ bhh0,
    const float* __restrict__ wih1, const float* __restrict__ bih1,
    const float* __restrict__ whh1, const float* __restrict__ bhh1,
    float* __restrict__ out, const int T)
{
  const int b = blockIdx.x, j = threadIdx.x;
  __shared__ float h0[16], h1[16];
  __shared__ float sr[16], sz[16], sni[16], snh[16];
  float w0r[16], w1i[16], w1r[16];
  float bh0 = 0.0f, bi1 = 0.0f, bh1 = 0.0f;
  if (j < 48) {
    #pragma unroll
    for (int k = 0; k < 16; ++k) {
      w0r[k] = whh0[j * 16 + k];
      w1i[k] = wih1[j * 16 + k];
      w1r[k] = whh1[j * 16 + k];
    }
    bh0 = bhh0[j]; bi1 = bih1[j]; bh1 = bhh1[j];
  }
  if (j < 16) { h0[j] = 0.0f; h1[j] = 0.0f; }
  const float* gib = GI + (size_t)b * T * 48;
  float gA = (j < 48) ? gib[j] : 0.0f;             // gi for t
  float gB = (j < 48) ? gib[48 + j] : 0.0f;        // gi for t+1
  __syncthreads();
  for (int t = 0; t < T; ++t) {
    float gnext = (j < 48 && (t + 2) < T) ? gib[(size_t)(t + 2) * 48 + j] : 0.0f;
    // ---- layer 0 ----
    float gh = bh0;
    #pragma unroll
    for (int k = 0; k < 16; ++k) gh += w0r[k] * h0[k];
    if (j < 32) {
      float a = gA + gh;
      float s = 1.0f / (1.0f + __expf(-a));
      if (j < 16) sr[j] = s; else sz[j - 16] = s;
    } else if (j < 48) {
      sni[j - 32] = gA; snh[j - 32] = gh;
    }
    __syncthreads();
    if (j < 16) {
      float r = sr[j], z = sz[j];
      float e = __expf(2.0f * (sni[j] + r * snh[j]));
      float n = 1.0f - 2.0f / (e + 1.0f);
      h0[j] = (1.0f - z) * n + z * h0[j];
    }
    __syncthreads();
    // ---- layer 1 (input = fresh h0) ----
    float gi1 = bi1, gh1 = bh1;
    #pragma unroll
    for (int k = 0; k < 16; ++k) {
      gi1 += w1i[k] * h0[k];
      gh1 += w1r[k] * h1[k];
    }
    if (j < 32) {
      float a = gi1 + gh1;
      float s = 1.0f / (1.0f + __expf(-a));
      if (j < 16) sr[j] = s; else sz[j - 16] = s;
    } else if (j < 48) {
      sni[j - 32] = gi1; snh[j - 32] = gh1;
    }
    __syncthreads();
    if (j < 16) {
      float r = sr[j], z = sz[j];
      float e = __expf(2.0f * (sni[j] + r * snh[j]));
      float n = 1.0f - 2.0f / (e + 1.0f);
      float hn = (1.0f - z) * n + z * h1[j];
      h1[j] = hn;
      out[((size_t)b * T + t) * 16 + j] = hn;
    }
    __syncthreads();
    gA = gB; gB = gnext;
  }
}

extern "C" void kernel_launch(void* const* d_in, const int* in_sizes, int n_in,
                              void* d_out, int out_size, void* d_ws, size_t ws_size,
                              hipStream_t stream) {
  (void)in_sizes; (void)n_in; (void)out_size; (void)ws_size;
  const float* x = (const float*)d_in[0];
  const float* w1 = (const float*)d_in[1];  const float* b1 = (const float*)d_in[2];
  const float* g1 = (const float*)d_in[3];  const float* bb1 = (const float*)d_in[4];
  const float* m1 = (const float*)d_in[5];  const float* v1 = (const float*)d_in[6];
  const float* w2 = (const float*)d_in[7];  const float* b2 = (const float*)d_in[8];
  const float* g2 = (const float*)d_in[9];  const float* bb2 = (const float*)d_in[10];
  const float* m2 = (const float*)d_in[11]; const float* v2 = (const float*)d_in[12];
  const float* w3 = (const float*)d_in[13]; const float* b3 = (const float*)d_in[14];
  const float* g3 = (const float*)d_in[15]; const float* bb3 = (const float*)d_in[16];
  const float* m3 = (const float*)d_in[17]; const float* v3 = (const float*)d_in[18];
  const float* w4 = (const float*)d_in[19]; const float* b4 = (const float*)d_in[20];
  const float* g4 = (const float*)d_in[21]; const float* bb4 = (const float*)d_in[22];
  const float* m4 = (const float*)d_in[23]; const float* v4 = (const float*)d_in[24];
  const float* w5 = (const float*)d_in[25]; const float* b5 = (const float*)d_in[26];
  const float* g5 = (const float*)d_in[27]; const float* bb5 = (const float*)d_in[28];
  const float* m5 = (const float*)d_in[29]; const float* v5 = (const float*)d_in[30];
  const float* wih0 = (const float*)d_in[31];
  const float* whh0 = (const float*)d_in[32];
  const float* bih0 = (const float*)d_in[33];
  const float* bhh0 = (const float*)d_in[34];
  const float* wih1 = (const float*)d_in[35];
  const float* whh1 = (const float*)d_in[36];
  const float* bih1 = (const float*)d_in[37];
  const float* bhh1 = (const float*)d_in[38];

  char* ws = (char*)d_ws;
  size_t off = 0;
  auto alloc = [&](size_t bytes) {
    size_t r = off;
    off = (off + bytes + 255) & ~(size_t)255;
    return r;
  };
  bf16_t* p1 = (bf16_t*)(ws + alloc((size_t)256 * 160 * 2));
  bf16_t* p2 = (bf16_t*)(ws + alloc((size_t)512 * 1280 * 2));
  bf16_t* p3 = (bf16_t*)(ws + alloc((size_t)256 * 2560 * 2));
  bf16_t* p4 = (bf16_t*)(ws + alloc((size_t)128 * 768 * 2));
  bf16_t* p5 = (bf16_t*)(ws + alloc((size_t)128 * 384 * 2));
  bf16_t* xp = (bf16_t*)(ws + alloc((size_t)32 * 4096 * 32 * 2));
  char* bufA = ws + alloc((size_t)32 * 4076 * 256 * 2);   // act1 / act3 / act5(fp32)
  char* bufB = ws + alloc((size_t)32 * 4056 * 512 * 2);   // act2 / act4 / gi0(fp32)

  bf16_t* a1 = (bf16_t*)bufA;
  bf16_t* a2 = (bf16_t*)bufB;
  bf16_t* a3 = (bf16_t*)bufA;
  bf16_t* a4 = (bf16_t*)bufB;
  float*  a5 = (float*)bufA;   // 32*4024*128*4 = 65.9MB <= bufA
  float*  gi = (float*)bufB;   // 32*4024*48*4  = 24.7MB <= bufB

  hipLaunchKernelGGL(pack_w_kernel, dim3(2560, 5), dim3(256), 0, stream,
                     w1, w2, w3, w4, w5, p1, p2, p3, p4, p5);
  hipLaunchKernelGGL(pack_x_kernel, dim3(16, 32), dim3(256), 0, stream, x, xp);

  hipLaunchKernelGGL((tdnn_gemm<32, 5, 5, false>), dim3(32, 2, 32), dim3(256), 0, stream,
                     xp, p1, b1, g1, bb1, m1, v1, a1, (float*)nullptr, 4096, 4076, 256);
  hipLaunchKernelGGL((tdnn_gemm<256, 5, 5, false>), dim3(32, 4, 32), dim3(256), 0, stream,
                     a1, p2, b2, g2, bb2, m2, v2, a2, (float*)nullptr, 4076, 4056, 512);
  hipLaunchKernelGGL((tdnn_gemm<512, 5, 5, false>), dim3(32, 2, 32), dim3(256), 0, stream,
                     a2, p3, b3, g3, bb3, m3, v3, a3, (float*)nullptr, 4056, 4036, 256);
  hipLaunchKernelGGL((tdnn_gemm<256, 3, 3, false>), dim3(32, 1, 32), dim3(256), 0, stream,
                     a3, p4, b4, g4, bb4, m4, v4, a4, (float*)nullptr, 4036, 4030, 128);
  hipLaunchKernelGGL((tdnn_gemm<128, 3, 3, true>), dim3(32, 1, 32), dim3(256), 0, stream,
                     a4, p5, b5, g5, bb5, m5, v5, (bf16_t*)nullptr, a5, 4030, 4024, 128);

  hipLaunchKernelGGL(gi0_kernel, dim3(63, 32), dim3(256), 0, stream, a5, wih0, bih0, gi, 4024);
  hipLaunchKernelGGL(gru_kernel, dim3(32), dim3(64), 0, stream,
                     gi, whh0, bhh0, wih1, bih1, whh1, bhh1, (float*)d_out, 4024);
}

// Round 2
// 2394.168 us; speedup vs baseline: 1.6058x; 1.6058x over previous
//
#include <hip/hip_runtime.h>

typedef __bf16 bf16_t;
typedef __bf16 bf16x8 __attribute__((ext_vector_type(8)));
typedef float f32x4 __attribute__((ext_vector_type(4)));

#define EPSBN 1e-5f

__device__ __forceinline__ void gload16(const void* g, void* l) {
  __builtin_amdgcn_global_load_lds(
      (const __attribute__((address_space(1))) void*)g,
      (__attribute__((address_space(3))) void*)l, 16, 0, 0);
}

__device__ __forceinline__ float bcast(float v, int srcLane) {
  return __int_as_float(__builtin_amdgcn_readlane(__float_as_int(v), srcLane));
}

// ---------------- weight packing: fp32 -> bf16 (w1 padded 20->32 ch) ----------------
__global__ __launch_bounds__(256) void pack_w_kernel(
    const float* __restrict__ w1, const float* __restrict__ w2,
    const float* __restrict__ w3, const float* __restrict__ w4,
    const float* __restrict__ w5,
    bf16_t* __restrict__ p1, bf16_t* __restrict__ p2, bf16_t* __restrict__ p3,
    bf16_t* __restrict__ p4, bf16_t* __restrict__ p5)
{
  const int idx = blockIdx.x * 256 + threadIdx.x;
  switch (blockIdx.y) {
    case 0:
      if (idx < 256 * 160) {
        int o = idx / 160, k = idx % 160, tap = k / 32, ch = k % 32;
        p1[idx] = (bf16_t)((ch < 20) ? w1[o * 100 + tap * 20 + ch] : 0.0f);
      }
      break;
    case 1: if (idx < 512 * 1280) p2[idx] = (bf16_t)w2[idx]; break;
    case 2: if (idx < 256 * 2560) p3[idx] = (bf16_t)w3[idx]; break;
    case 3: if (idx < 128 * 768)  p4[idx] = (bf16_t)w4[idx]; break;
    default: if (idx < 128 * 384) p5[idx] = (bf16_t)w5[idx]; break;
  }
}

// ---------------- x: (B,20,L) fp32 -> (B,L,32) bf16, zero-padded channels ----------------
__global__ __launch_bounds__(256) void pack_x_kernel(
    const float* __restrict__ x, bf16_t* __restrict__ xp)
{
  __shared__ __align__(16) bf16_t Ls[256 * 32];
  const int tid = threadIdx.x;
  const int b = blockIdx.y;
  const int l0 = blockIdx.x * 256;
  bf16x8 z = {};
  #pragma unroll
  for (int i = 0; i < 4; ++i) ((bf16x8*)Ls)[tid + i * 256] = z;
  __syncthreads();
  #pragma unroll
  for (int ch = 0; ch < 20; ++ch) {
    float v = x[((size_t)b * 20 + ch) * 4096 + l0 + tid];
    Ls[tid * 32 + ch] = (bf16_t)v;
  }
  __syncthreads();
  bf16x8* dst = (bf16x8*)(xp + ((size_t)b * 4096 + l0) * 32);
  #pragma unroll
  for (int i = 0; i < 4; ++i) dst[tid + i * 256] = ((bf16x8*)Ls)[tid + i * 256];
}

// ---------------- TDNN layer as MFMA GEMM over dilated taps ----------------
template <int DIN, int C, int DIL, bool OUTF32>
__global__ __launch_bounds__(256, 2) void tdnn_gemm(
    const bf16_t* __restrict__ X, const bf16_t* __restrict__ W,
    const float* __restrict__ bias, const float* __restrict__ gg,
    const float* __restrict__ bb, const float* __restrict__ mm,
    const float* __restrict__ vv,
    bf16_t* __restrict__ Yb, float* __restrict__ Yf,
    const int Lin, const int Lo, const int N)
{
  __shared__ __align__(16) bf16_t As[128 * 32];
  __shared__ __align__(16) bf16_t Bs[128 * 32];
  const int tid = threadIdx.x;
  const int wave = tid >> 6;
  const int lane = tid & 63;
  const int l0 = blockIdx.x * 128;
  const int n0 = blockIdx.y * 128;
  const int b = blockIdx.z;
  const int lm = lane & 15;
  const int quad = lane >> 4;
  const int wm = (wave >> 1) * 64;
  const int wn = (wave & 1) * 64;
  constexpr int Ktot = C * DIN;

  const int srow = wave * 32 + (lane >> 2);
  const int scol = (lane & 3) * 8;

  const int rA0 = min(l0 + srow, Lo - 1);
  const int rA1 = min(l0 + srow + 16, Lo - 1);

  const bf16_t* Xb = X + (size_t)b * Lin * DIN;
  const bf16_t* xg0 = Xb + (size_t)rA0 * DIN + scol;
  const bf16_t* xg1 = Xb + (size_t)rA1 * DIN + scol;
  const bf16_t* wg0 = W + (size_t)(n0 + srow) * Ktot + scol;
  const bf16_t* wg1 = W + (size_t)(n0 + srow + 16) * Ktot + scol;

  bf16_t* AsW = &As[(wave * 32) * 32];
  bf16_t* BsW = &Bs[(wave * 32) * 32];

  f32x4 acc[4][4];
  f32x4 zz = {};
  #pragma unroll
  for (int i = 0; i < 4; ++i)
    #pragma unroll
    for (int j = 0; j < 4; ++j) acc[i][j] = zz;

  for (int tap = 0; tap < C; ++tap) {
    const bf16_t* xa0 = xg0 + (size_t)tap * DIL * DIN;
    const bf16_t* xa1 = xg1 + (size_t)tap * DIL * DIN;
    const bf16_t* wa0 = wg0 + tap * DIN;
    const bf16_t* wa1 = wg1 + tap * DIN;
    for (int kc = 0; kc < DIN / 32; ++kc) {
      gload16(xa0 + kc * 32, AsW);
      gload16(xa1 + kc * 32, AsW + 16 * 32);
      gload16(wa0 + kc * 32, BsW);
      gload16(wa1 + kc * 32, BsW + 16 * 32);
      __syncthreads();
      bf16x8 av[4], bv[4];
      #pragma unroll
      for (int mt = 0; mt < 4; ++mt)
        av[mt] = *(const bf16x8*)&As[(wm + mt * 16 + lm) * 32 + quad * 8];
      #pragma unroll
      for (int nt = 0; nt < 4; ++nt)
        bv[nt] = *(const bf16x8*)&Bs[(wn + nt * 16 + lm) * 32 + quad * 8];
      #pragma unroll
      for (int mt = 0; mt < 4; ++mt)
        #pragma unroll
        for (int nt = 0; nt < 4; ++nt)
          acc[mt][nt] = __builtin_amdgcn_mfma_f32_16x16x32_bf16(av[mt], bv[nt], acc[mt][nt], 0, 0, 0);
      __syncthreads();
    }
  }

  #pragma unroll
  for (int nt = 0; nt < 4; ++nt) {
    const int col = n0 + wn + nt * 16 + lm;
    const float sc = gg[col] * rsqrtf(vv[col] + EPSBN);
    const float sh = bb[col] - mm[col] * sc;
    const float bi = bias[col];
    #pragma unroll
    for (int mt = 0; mt < 4; ++mt) {
      const int rbase = l0 + wm + mt * 16 + quad * 4;
      #pragma unroll
      for (int r = 0; r < 4; ++r) {
        const int row = rbase + r;
        if (row < Lo) {
          float val = fmaxf(acc[mt][nt][r] + bi, 0.0f) * sc + sh;
          const size_t oi = ((size_t)b * Lo + row) * N + col;
          if constexpr (OUTF32) Yf[oi] = val;
          else                  Yb[oi] = (bf16_t)val;
        }
      }
    }
  }
}

// ---------------- gi0 = act5 @ wih0^T + bih0, fp32 ----------------
__global__ __launch_bounds__(256, 2) void gi0_kernel(
    const float* __restrict__ A5, const float* __restrict__ wih,
    const float* __restrict__ bih, float* __restrict__ GI, const int T)
{
  __shared__ __align__(16) float Xs[64 * 132];
  __shared__ __align__(16) float Ws[48 * 132];
  const int tid = threadIdx.x;
  const int b = blockIdx.y, t0 = blockIdx.x * 64;
  for (int c = tid; c < 48 * 32; c += 256) {
    int j = c >> 5, k4 = c & 31;
    *(float4*)&Ws[j * 132 + k4 * 4] = *(const float4*)&wih[j * 128 + k4 * 4];
  }
  for (int c = tid; c < 64 * 32; c += 256) {
    int r = c >> 5, k4 = c & 31;
    int tt = min(t0 + r, T - 1);
    *(float4*)&Xs[r * 132 + k4 * 4] = *(const float4*)&A5[((size_t)b * T + tt) * 128 + k4 * 4];
  }
  __syncthreads();
  const int tl = tid >> 2, jg = tid & 3;
  float acc[12];
  #pragma unroll
  for (int i = 0; i < 12; ++i) acc[i] = 0.0f;
  for (int k = 0; k < 128; k += 4) {
    float4 xv = *(const float4*)&Xs[tl * 132 + k];
    #pragma unroll
    for (int jj = 0; jj < 12; ++jj) {
      float4 wv = *(const float4*)&Ws[(jg * 12 + jj) * 132 + k];
      acc[jj] += xv.x * wv.x + xv.y * wv.y + xv.z * wv.z + xv.w * wv.w;
    }
  }
  const int t = t0 + tl;
  if (t < T) {
    float* dst = &GI[((size_t)b * T + t) * 48 + jg * 12];
    #pragma unroll
    for (int jj = 0; jj < 12; ++jj) dst[jj] = acc[jj] + bih[jg * 12 + jj];
  }
}

// ---------------- fused 2-layer GRU: register-resident, barrier-free ----------------
// One wave per batch. Lane u (0..15): layer0 unit u. Lane 16+u: layer1 unit u.
// Layer1 runs one step behind layer0 (pipeline skew 1); both consume the same
// SGPR broadcast sh0 = h0(i-1) each iteration (layer0 recurrent, layer1 input).
__global__ __launch_bounds__(64, 1) void gru_kernel(
    const float* __restrict__ GI,
    const float* __restrict__ whh0, const float* __restrict__ bhh0,
    const float* __restrict__ wih1, const float* __restrict__ bih1,
    const float* __restrict__ whh1, const float* __restrict__ bhh1,
    float* __restrict__ out, const int T)
{
  const int b = blockIdx.x;
  const int lane = threadIdx.x;
  const int u = lane & 15;
  const int role = lane >> 4;          // 0: layer0, 1: layer1, 2/3: idle

  // per-lane weight rows: chain1 over sh0, chain2 over sh1
  float w1r[16], w1z[16], w1n[16], w2r[16], w2z[16], w2n[16];
  float i1r = 0.f, i1z = 0.f, i1n = 0.f, i2r = 0.f, i2z = 0.f, i2n = 0.f;
  if (role == 0) {
    #pragma unroll
    for (int k = 0; k < 16; ++k) {
      w1r[k] = whh0[(u) * 16 + k];
      w1z[k] = whh0[(16 + u) * 16 + k];
      w1n[k] = whh0[(32 + u) * 16 + k];
      w2r[k] = 0.f; w2z[k] = 0.f; w2n[k] = 0.f;
    }
    i1r = bhh0[u]; i1z = bhh0[16 + u]; i1n = bhh0[32 + u];
  } else if (role == 1) {
    #pragma unroll
    for (int k = 0; k < 16; ++k) {
      w1r[k] = wih1[(u) * 16 + k];
      w1z[k] = wih1[(16 + u) * 16 + k];
      w1n[k] = wih1[(32 + u) * 16 + k];
      w2r[k] = whh1[(u) * 16 + k];
      w2z[k] = whh1[(16 + u) * 16 + k];
      w2n[k] = whh1[(32 + u) * 16 + k];
    }
    i1r = bih1[u]; i1z = bih1[16 + u]; i1n = bih1[32 + u];
    i2r = bhh1[u]; i2z = bhh1[16 + u]; i2n = bhh1[32 + u];
  } else {
    #pragma unroll
    for (int k = 0; k < 16; ++k) {
      w1r[k] = 0.f; w1z[k] = 0.f; w1n[k] = 0.f;
      w2r[k] = 0.f; w2z[k] = 0.f; w2n[k] = 0.f;
    }
  }
  const bool L1 = (role == 1);

  const float* gib = GI + (size_t)b * T * 48;
  // gi register pipeline, depth 2: (gr0,gz0,gn0)=step i, (gr1,...)=step i+1
  float gr0 = gib[u],            gz0 = gib[16 + u],      gn0 = gib[32 + u];
  float gr1 = gib[48 + u],       gz1 = gib[48 + 16 + u], gn1 = gib[48 + 32 + u];

  float hreg = 0.f;                       // lane u: h0[u]; lane 16+u: h1[u]
  float sh0[16], sh1[16];
  #pragma unroll
  for (int k = 0; k < 16; ++k) { sh0[k] = 0.f; sh1[k] = 0.f; }

  for (int i = 0; i <= T; ++i) {
    // prefetch gi for step i+2
    const int tp = min(i + 2, T - 1);
    const float* gp = gib + (size_t)tp * 48 + u;
    const float gr2 = gp[0], gz2 = gp[16], gn2 = gp[32];

    // matvec chains (lane-uniform): c1 over sh0, c2 over sh1
    float c1r = i1r, c1z = i1z, c1n = i1n;
    float c2r = i2r, c2z = i2z, c2n = i2n;
    #pragma unroll
    for (int k = 0; k < 16; ++k) {
      const float a = sh0[k], bb_ = sh1[k];
      c1r += w1r[k] * a;  c1z += w1z[k] * a;  c1n += w1n[k] * a;
      c2r += w2r[k] * bb_; c2z += w2z[k] * bb_; c2n += w2n[k] * bb_;
    }

    // per-layer role assignment
    const float aIr = L1 ? c1r : gr0;  const float aRr = L1 ? c2r : c1r;
    const float aIz = L1 ? c1z : gz0;  const float aRz = L1 ? c2z : c1z;
    const float aIn = L1 ? c1n : gn0;  const float aRn = L1 ? c2n : c1n;

    const float r = 1.0f / (1.0f + __expf(-(aIr + aRr)));
    const float z = 1.0f / (1.0f + __expf(-(aIz + aRz)));
    const float e = __expf(2.0f * (aIn + r * aRn));
    const float n = 1.0f - 2.0f / (e + 1.0f);
    float hnew = (1.0f - z) * n + z * hreg;

    if (i == 0 && L1) hnew = 0.f;        // layer1 h init (pipeline warm-up)
    hreg = hnew;

    if (i > 0 && role == 1)
      out[((size_t)b * T + (i - 1)) * 16 + u] = hnew;

    // broadcast h0(i) (lanes 0..15) and h1(i-1) (lanes 16..31) to SGPRs
    #pragma unroll
    for (int k = 0; k < 16; ++k) {
      sh0[k] = bcast(hreg, k);
      sh1[k] = bcast(hreg, 16 + k);
    }

    gr0 = gr1; gz0 = gz1; gn0 = gn1;
    gr1 = gr2; gz1 = gz2; gn1 = gn2;
  }
}

extern "C" void kernel_launch(void* const* d_in, const int* in_sizes, int n_in,
                              void* d_out, int out_size, void* d_ws, size_t ws_size,
                              hipStream_t stream) {
  (void)in_sizes; (void)n_in; (void)out_size; (void)ws_size;
  const float* x = (const float*)d_in[0];
  const float* w1 = (const float*)d_in[1];  const float* b1 = (const float*)d_in[2];
  const float* g1 = (const float*)d_in[3];  const float* bb1 = (const float*)d_in[4];
  const float* m1 = (const float*)d_in[5];  const float* v1 = (const float*)d_in[6];
  const float* w2 = (const float*)d_in[7];  const float* b2 = (const float*)d_in[8];
  const float* g2 = (const float*)d_in[9];  const float* bb2 = (const float*)d_in[10];
  const float* m2 = (const float*)d_in[11]; const float* v2 = (const float*)d_in[12];
  const float* w3 = (const float*)d_in[13]; const float* b3 = (const float*)d_in[14];
  const float* g3 = (const float*)d_in[15]; const float* bb3 = (const float*)d_in[16];
  const float* m3 = (const float*)d_in[17]; const float* v3 = (const float*)d_in[18];
  const float* w4 = (const float*)d_in[19]; const float* b4 = (const float*)d_in[20];
  const float* g4 = (const float*)d_in[21]; const float* bb4 = (const float*)d_in[22];
  const float* m4 = (const float*)d_in[23]; const float* v4 = (const float*)d_in[24];
  const float* w5 = (const float*)d_in[25]; const float* b5 = (const float*)d_in[26];
  const float* g5 = (const float*)d_in[27]; const float* bb5 = (const float*)d_in[28];
  const float* m5 = (const float*)d_in[29]; const float* v5 = (const float*)d_in[30];
  const float* wih0 = (const float*)d_in[31];
  const float* whh0 = (const float*)d_in[32];
  const float* bih0 = (const float*)d_in[33];
  const float* bhh0 = (const float*)d_in[34];
  const float* wih1 = (const float*)d_in[35];
  const float* whh1 = (const float*)d_in[36];
  const float* bih1 = (const float*)d_in[37];
  const float* bhh1 = (const float*)d_in[38];

  char* ws = (char*)d_ws;
  size_t off = 0;
  auto alloc = [&](size_t bytes) {
    size_t r = off;
    off = (off + bytes + 255) & ~(size_t)255;
    return r;
  };
  bf16_t* p1 = (bf16_t*)(ws + alloc((size_t)256 * 160 * 2));
  bf16_t* p2 = (bf16_t*)(ws + alloc((size_t)512 * 1280 * 2));
  bf16_t* p3 = (bf16_t*)(ws + alloc((size_t)256 * 2560 * 2));
  bf16_t* p4 = (bf16_t*)(ws + alloc((size_t)128 * 768 * 2));
  bf16_t* p5 = (bf16_t*)(ws + alloc((size_t)128 * 384 * 2));
  bf16_t* xp = (bf16_t*)(ws + alloc((size_t)32 * 4096 * 32 * 2));
  char* bufA = ws + alloc((size_t)32 * 4076 * 256 * 2);
  char* bufB = ws + alloc((size_t)32 * 4056 * 512 * 2);

  bf16_t* a1 = (bf16_t*)bufA;
  bf16_t* a2 = (bf16_t*)bufB;
  bf16_t* a3 = (bf16_t*)bufA;
  bf16_t* a4 = (bf16_t*)bufB;
  float*  a5 = (float*)bufA;
  float*  gi = (float*)bufB;

  hipLaunchKernelGGL(pack_w_kernel, dim3(2560, 5), dim3(256), 0, stream,
                     w1, w2, w3, w4, w5, p1, p2, p3, p4, p5);
  hipLaunchKernelGGL(pack_x_kernel, dim3(16, 32), dim3(256), 0, stream, x, xp);

  hipLaunchKernelGGL((tdnn_gemm<32, 5, 5, false>), dim3(32, 2, 32), dim3(256), 0, stream,
                     xp, p1, b1, g1, bb1, m1, v1, a1, (float*)nullptr, 4096, 4076, 256);
  hipLaunchKernelGGL((tdnn_gemm<256, 5, 5, false>), dim3(32, 4, 32), dim3(256), 0, stream,
                     a1, p2, b2, g2, bb2, m2, v2, a2, (float*)nullptr, 4076, 4056, 512);
  hipLaunchKernelGGL((tdnn_gemm<512, 5, 5, false>), dim3(32, 2, 32), dim3(256), 0, stream,
                     a2, p3, b3, g3, bb3, m3, v3, a3, (float*)nullptr, 4056, 4036, 256);
  hipLaunchKernelGGL((tdnn_gemm<256, 3, 3, false>), dim3(32, 1, 32), dim3(256), 0, stream,
                     a3, p4, b4, g4, bb4, m4, v4, a4, (float*)nullptr, 4036, 4030, 128);
  hipLaunchKernelGGL((tdnn_gemm<128, 3, 3, true>), dim3(32, 1, 32), dim3(256), 0, stream,
                     a4, p5, b5, g5, bb5, m5, v5, (bf16_t*)nullptr, a5, 4030, 4024, 128);

  hipLaunchKernelGGL(gi0_kernel, dim3(63, 32), dim3(256), 0, stream, a5, wih0, bih0, gi, 4024);
  hipLaunchKernelGGL(gru_kernel, dim3(32), dim3(64), 0, stream,
                     gi, whh0, bhh0, wih1, bih1, whh1, bhh1, (float*)d_out, 4024);
}

// Round 4
// 2113.768 us; speedup vs baseline: 1.8189x; 1.1327x over previous
//
#include <hip/hip_runtime.h>

typedef __bf16 bf16_t;
typedef __bf16 bf16x8 __attribute__((ext_vector_type(8)));
typedef float f32x4 __attribute__((ext_vector_type(4)));
typedef __fp16 f16x2 __attribute__((ext_vector_type(2)));

#define EPSBN 1e-5f

__device__ __forceinline__ void gload16(const void* g, void* l) {
  __builtin_amdgcn_global_load_lds(
      (const __attribute__((address_space(1))) void*)g,
      (__attribute__((address_space(3))) void*)l, 16, 0, 0);
}

__device__ __forceinline__ f16x2 i2h(int x) { union { int i; f16x2 h; } u; u.i = x; return u.h; }
__device__ __forceinline__ int h2i(f16x2 x) { union { int i; f16x2 h; } u; u.h = x; return u.i; }

__device__ __forceinline__ float dot2acc(f16x2 w, f16x2 h, float acc) {
#if __has_builtin(__builtin_amdgcn_fdot2)
  return __builtin_amdgcn_fdot2(w, h, acc, false);
#else
  return acc + (float)w[0] * (float)h[0] + (float)w[1] * (float)h[1];
#endif
}

// ---------------- weight packing: fp32 -> bf16 (w1 padded 20->32 ch) ----------------
__global__ __launch_bounds__(256) void pack_w_kernel(
    const float* __restrict__ w1, const float* __restrict__ w2,
    const float* __restrict__ w3, const float* __restrict__ w4,
    const float* __restrict__ w5,
    bf16_t* __restrict__ p1, bf16_t* __restrict__ p2, bf16_t* __restrict__ p3,
    bf16_t* __restrict__ p4, bf16_t* __restrict__ p5)
{
  const int idx = blockIdx.x * 256 + threadIdx.x;
  switch (blockIdx.y) {
    case 0:
      if (idx < 256 * 160) {
        int o = idx / 160, k = idx % 160, tap = k / 32, ch = k % 32;
        p1[idx] = (bf16_t)((ch < 20) ? w1[o * 100 + tap * 20 + ch] : 0.0f);
      }
      break;
    case 1: if (idx < 512 * 1280) p2[idx] = (bf16_t)w2[idx]; break;
    case 2: if (idx < 256 * 2560) p3[idx] = (bf16_t)w3[idx]; break;
    case 3: if (idx < 128 * 768)  p4[idx] = (bf16_t)w4[idx]; break;
    default: if (idx < 128 * 384) p5[idx] = (bf16_t)w5[idx]; break;
  }
}

// ---------------- x: (B,20,L) fp32 -> (B,L,32) bf16, zero-padded channels ----------------
__global__ __launch_bounds__(256) void pack_x_kernel(
    const float* __restrict__ x, bf16_t* __restrict__ xp)
{
  __shared__ __align__(16) bf16_t Ls[256 * 32];
  const int tid = threadIdx.x;
  const int b = blockIdx.y;
  const int l0 = blockIdx.x * 256;
  bf16x8 z = {};
  #pragma unroll
  for (int i = 0; i < 4; ++i) ((bf16x8*)Ls)[tid + i * 256] = z;
  __syncthreads();
  #pragma unroll
  for (int ch = 0; ch < 20; ++ch) {
    float v = x[((size_t)b * 20 + ch) * 4096 + l0 + tid];
    Ls[tid * 32 + ch] = (bf16_t)v;
  }
  __syncthreads();
  bf16x8* dst = (bf16x8*)(xp + ((size_t)b * 4096 + l0) * 32);
  #pragma unroll
  for (int i = 0; i < 4; ++i) dst[tid + i * 256] = ((bf16x8*)Ls)[tid + i * 256];
}

// ---------------- TDNN layer as MFMA GEMM over dilated taps ----------------
template <int DIN, int C, int DIL, bool OUTF32>
__global__ __launch_bounds__(256, 2) void tdnn_gemm(
    const bf16_t* __restrict__ X, const bf16_t* __restrict__ W,
    const float* __restrict__ bias, const float* __restrict__ gg,
    const float* __restrict__ bb, const float* __restrict__ mm,
    const float* __restrict__ vv,
    bf16_t* __restrict__ Yb, float* __restrict__ Yf,
    const int Lin, const int Lo, const int N)
{
  __shared__ __align__(16) bf16_t As[128 * 32];
  __shared__ __align__(16) bf16_t Bs[128 * 32];
  const int tid = threadIdx.x;
  const int wave = tid >> 6;
  const int lane = tid & 63;
  const int l0 = blockIdx.x * 128;
  const int n0 = blockIdx.y * 128;
  const int b = blockIdx.z;
  const int lm = lane & 15;
  const int quad = lane >> 4;
  const int wm = (wave >> 1) * 64;
  const int wn = (wave & 1) * 64;
  constexpr int Ktot = C * DIN;

  const int srow = wave * 32 + (lane >> 2);
  const int scol = (lane & 3) * 8;

  const int rA0 = min(l0 + srow, Lo - 1);
  const int rA1 = min(l0 + srow + 16, Lo - 1);

  const bf16_t* Xb = X + (size_t)b * Lin * DIN;
  const bf16_t* xg0 = Xb + (size_t)rA0 * DIN + scol;
  const bf16_t* xg1 = Xb + (size_t)rA1 * DIN + scol;
  const bf16_t* wg0 = W + (size_t)(n0 + srow) * Ktot + scol;
  const bf16_t* wg1 = W + (size_t)(n0 + srow + 16) * Ktot + scol;

  bf16_t* AsW = &As[(wave * 32) * 32];
  bf16_t* BsW = &Bs[(wave * 32) * 32];

  f32x4 acc[4][4];
  f32x4 zz = {};
  #pragma unroll
  for (int i = 0; i < 4; ++i)
    #pragma unroll
    for (int j = 0; j < 4; ++j) acc[i][j] = zz;

  for (int tap = 0; tap < C; ++tap) {
    const bf16_t* xa0 = xg0 + (size_t)tap * DIL * DIN;
    const bf16_t* xa1 = xg1 + (size_t)tap * DIL * DIN;
    const bf16_t* wa0 = wg0 + tap * DIN;
    const bf16_t* wa1 = wg1 + tap * DIN;
    for (int kc = 0; kc < DIN / 32; ++kc) {
      gload16(xa0 + kc * 32, AsW);
      gload16(xa1 + kc * 32, AsW + 16 * 32);
      gload16(wa0 + kc * 32, BsW);
      gload16(wa1 + kc * 32, BsW + 16 * 32);
      __syncthreads();
      bf16x8 av[4], bv[4];
      #pragma unroll
      for (int mt = 0; mt < 4; ++mt)
        av[mt] = *(const bf16x8*)&As[(wm + mt * 16 + lm) * 32 + quad * 8];
      #pragma unroll
      for (int nt = 0; nt < 4; ++nt)
        bv[nt] = *(const bf16x8*)&Bs[(wn + nt * 16 + lm) * 32 + quad * 8];
      #pragma unroll
      for (int mt = 0; mt < 4; ++mt)
        #pragma unroll
        for (int nt = 0; nt < 4; ++nt)
          acc[mt][nt] = __builtin_amdgcn_mfma_f32_16x16x32_bf16(av[mt], bv[nt], acc[mt][nt], 0, 0, 0);
      __syncthreads();
    }
  }

  #pragma unroll
  for (int nt = 0; nt < 4; ++nt) {
    const int col = n0 + wn + nt * 16 + lm;
    const float sc = gg[col] * rsqrtf(vv[col] + EPSBN);
    const float sh = bb[col] - mm[col] * sc;
    const float bi = bias[col];
    #pragma unroll
    for (int mt = 0; mt < 4; ++mt) {
      const int rbase = l0 + wm + mt * 16 + quad * 4;
      #pragma unroll
      for (int r = 0; r < 4; ++r) {
        const int row = rbase + r;
        if (row < Lo) {
          float val = fmaxf(acc[mt][nt][r] + bi, 0.0f) * sc + sh;
          const size_t oi = ((size_t)b * Lo + row) * N + col;
          if constexpr (OUTF32) Yf[oi] = val;
          else                  Yb[oi] = (bf16_t)val;
        }
      }
    }
  }
}

// ---------------- gi0 = act5 @ wih0^T + bih0, fp32; n-gate rows (32..47) pre-scaled x2 ----------------
__global__ __launch_bounds__(256, 2) void gi0_kernel(
    const float* __restrict__ A5, const float* __restrict__ wih,
    const float* __restrict__ bih, float* __restrict__ GI, const int T)
{
  __shared__ __align__(16) float Xs[64 * 132];
  __shared__ __align__(16) float Ws[48 * 132];
  const int tid = threadIdx.x;
  const int b = blockIdx.y, t0 = blockIdx.x * 64;
  for (int c = tid; c < 48 * 32; c += 256) {
    int j = c >> 5, k4 = c & 31;
    *(float4*)&Ws[j * 132 + k4 * 4] = *(const float4*)&wih[j * 128 + k4 * 4];
  }
  for (int c = tid; c < 64 * 32; c += 256) {
    int r = c >> 5, k4 = c & 31;
    int tt = min(t0 + r, T - 1);
    *(float4*)&Xs[r * 132 + k4 * 4] = *(const float4*)&A5[((size_t)b * T + tt) * 128 + k4 * 4];
  }
  __syncthreads();
  const int tl = tid >> 2, jg = tid & 3;
  float acc[12];
  #pragma unroll
  for (int i = 0; i < 12; ++i) acc[i] = 0.0f;
  for (int k = 0; k < 128; k += 4) {
    float4 xv = *(const float4*)&Xs[tl * 132 + k];
    #pragma unroll
    for (int jj = 0; jj < 12; ++jj) {
      float4 wv = *(const float4*)&Ws[(jg * 12 + jj) * 132 + k];
      acc[jj] += xv.x * wv.x + xv.y * wv.y + xv.z * wv.z + xv.w * wv.w;
    }
  }
  const int t = t0 + tl;
  if (t < T) {
    float* dst = &GI[((size_t)b * T + t) * 48 + jg * 12];
    #pragma unroll
    for (int jj = 0; jj < 12; ++jj) {
      const int row = jg * 12 + jj;
      const float s = (row >= 32) ? 2.0f : 1.0f;   // fold tanh's 2x into n-gate gi
      dst[jj] = (acc[jj] + bih[row]) * s;
    }
  }
}

// ---------------- fused 2-layer GRU: packed-f16 dot2, register-resident, barrier-free ----------------
// One wave per batch. Lane u (0..15): layer0 unit u. Lane 16+u: layer1 unit u (1 step behind).
// h broadcast as packed f16 pairs via shfl_xor + cvt_pkrtz + 16 readlanes.
__global__ __launch_bounds__(64, 1) void gru_kernel(
    const float* __restrict__ GI,
    const float* __restrict__ whh0, const float* __restrict__ bhh0,
    const float* __restrict__ wih1, const float* __restrict__ bih1,
    const float* __restrict__ whh1, const float* __restrict__ bhh1,
    float* __restrict__ out, const int T)
{
  const int b = blockIdx.x;
  const int lane = threadIdx.x;
  const int u = lane & 15;
  const int role = lane >> 4;
  const bool L1 = (role == 1);

  f16x2 w1r[8], w1z[8], w1n[8], w2r[8], w2z[8], w2n[8];
  float i1r = 0.f, i1z = 0.f, i1n = 0.f, i2r = 0.f, i2z = 0.f, i2n = 0.f;
  const f16x2 hz0 = i2h(0);
  #pragma unroll
  for (int m = 0; m < 8; ++m) {
    w1r[m] = hz0; w1z[m] = hz0; w1n[m] = hz0;
    w2r[m] = hz0; w2z[m] = hz0; w2n[m] = hz0;
  }
  if (role == 0) {
    #pragma unroll
    for (int m = 0; m < 8; ++m) {
      w1r[m] = __builtin_amdgcn_cvt_pkrtz(whh0[u * 16 + 2 * m],            whh0[u * 16 + 2 * m + 1]);
      w1z[m] = __builtin_amdgcn_cvt_pkrtz(whh0[(16 + u) * 16 + 2 * m],     whh0[(16 + u) * 16 + 2 * m + 1]);
      w1n[m] = __builtin_amdgcn_cvt_pkrtz(2.f * whh0[(32 + u) * 16 + 2 * m], 2.f * whh0[(32 + u) * 16 + 2 * m + 1]);
    }
    i1r = bhh0[u]; i1z = bhh0[16 + u]; i1n = 2.f * bhh0[32 + u];
  } else if (role == 1) {
    #pragma unroll
    for (int m = 0; m < 8; ++m) {
      w1r[m] = __builtin_amdgcn_cvt_pkrtz(wih1[u * 16 + 2 * m],            wih1[u * 16 + 2 * m + 1]);
      w1z[m] = __builtin_amdgcn_cvt_pkrtz(wih1[(16 + u) * 16 + 2 * m],     wih1[(16 + u) * 16 + 2 * m + 1]);
      w1n[m] = __builtin_amdgcn_cvt_pkrtz(2.f * wih1[(32 + u) * 16 + 2 * m], 2.f * wih1[(32 + u) * 16 + 2 * m + 1]);
      w2r[m] = __builtin_amdgcn_cvt_pkrtz(whh1[u * 16 + 2 * m],            whh1[u * 16 + 2 * m + 1]);
      w2z[m] = __builtin_amdgcn_cvt_pkrtz(whh1[(16 + u) * 16 + 2 * m],     whh1[(16 + u) * 16 + 2 * m + 1]);
      w2n[m] = __builtin_amdgcn_cvt_pkrtz(2.f * whh1[(32 + u) * 16 + 2 * m], 2.f * whh1[(32 + u) * 16 + 2 * m + 1]);
    }
    i1r = bih1[u]; i1z = bih1[16 + u]; i1n = 2.f * bih1[32 + u];
    i2r = bhh1[u]; i2z = bhh1[16 + u]; i2n = 2.f * bhh1[32 + u];
  }

  const float* gib = GI + (size_t)b * T * 48;
  // gi register pipeline, depth 3
  float g0r = gib[u],          g0z = gib[16 + u],          g0n = gib[32 + u];
  float g1r = gib[48 + u],     g1z = gib[48 + 16 + u],     g1n = gib[48 + 32 + u];
  float g2r = gib[96 + u],     g2z = gib[96 + 16 + u],     g2n = gib[96 + 32 + u];

  float hreg = 0.f;                 // lane u: h0[u]; lane 16+u: h1[u]
  f16x2 s0[8], s1[8];
  #pragma unroll
  for (int m = 0; m < 8; ++m) { s0[m] = hz0; s1[m] = hz0; }

  for (int i = 0; i <= T; ++i) {
    // prefetch gi for step i+3
    const int tp = min(i + 3, T - 1);
    const float* gp = gib + (size_t)tp * 48 + u;
    const float g3r = gp[0], g3z = gp[16], g3n = gp[32];

    // matvec chains: c1 over s0 (h0), c2 over s1 (h1)
    float c1r = i1r, c1z = i1z, c1n = i1n;
    float c2r = i2r, c2z = i2z, c2n = i2n;
    #pragma unroll
    for (int m = 0; m < 8; ++m) {
      c1r = dot2acc(w1r[m], s0[m], c1r);
      c1z = dot2acc(w1z[m], s0[m], c1z);
      c1n = dot2acc(w1n[m], s0[m], c1n);
      c2r = dot2acc(w2r[m], s1[m], c2r);
      c2z = dot2acc(w2z[m], s1[m], c2z);
      c2n = dot2acc(w2n[m], s1[m], c2n);
    }

    const float aIr = L1 ? c1r : g0r;  const float aRr = L1 ? c2r : c1r;
    const float aIz = L1 ? c1z : g0z;  const float aRz = L1 ? c2z : c1z;
    const float aIn = L1 ? c1n : g0n;  const float aRn = L1 ? c2n : c1n;

    const float r = 1.0f / (1.0f + __expf(-(aIr + aRr)));
    const float z = 1.0f / (1.0f + __expf(-(aIz + aRz)));
    // n-gate: weights/bias/gi pre-scaled by 2 -> e = exp(2*(in + r*hn))
    const float e = __expf(aIn + r * aRn);
    const float n = 1.0f - 2.0f / (e + 1.0f);
    float hnew = n + z * (hreg - n);

    if (i == 0 && L1) hnew = 0.f;    // layer-1 pipeline warm-up
    hreg = hnew;

    if (i > 0 && L1)
      out[((size_t)b * T + (i - 1)) * 16 + u] = hnew;

    // pack pair (h[2m], h[2m+1]) into f16x2 on every lane, then 16 readlanes
    const float hp = __shfl_xor(hreg, 1);
    const f16x2 pk = (lane & 1) ? __builtin_amdgcn_cvt_pkrtz(hp, hreg)
                                : __builtin_amdgcn_cvt_pkrtz(hreg, hp);
    const int pki = h2i(pk);
    #pragma unroll
    for (int m = 0; m < 8; ++m) {
      s0[m] = i2h(__builtin_amdgcn_readlane(pki, 2 * m));
      s1[m] = i2h(__builtin_amdgcn_readlane(pki, 16 + 2 * m));
    }

    g0r = g1r; g0z = g1z; g0n = g1n;
    g1r = g2r; g1z = g2z; g1n = g2n;
    g2r = g3r; g2z = g3z; g2n = g3n;
  }
}

extern "C" void kernel_launch(void* const* d_in, const int* in_sizes, int n_in,
                              void* d_out, int out_size, void* d_ws, size_t ws_size,
                              hipStream_t stream) {
  (void)in_sizes; (void)n_in; (void)out_size; (void)ws_size;
  const float* x = (const float*)d_in[0];
  const float* w1 = (const float*)d_in[1];  const float* b1 = (const float*)d_in[2];
  const float* g1 = (const float*)d_in[3];  const float* bb1 = (const float*)d_in[4];
  const float* m1 = (const float*)d_in[5];  const float* v1 = (const float*)d_in[6];
  const float* w2 = (const float*)d_in[7];  const float* b2 = (const float*)d_in[8];
  const float* g2 = (const float*)d_in[9];  const float* bb2 = (const float*)d_in[10];
  const float* m2 = (const float*)d_in[11]; const float* v2 = (const float*)d_in[12];
  const float* w3 = (const float*)d_in[13]; const float* b3 = (const float*)d_in[14];
  const float* g3 = (const float*)d_in[15]; const float* bb3 = (const float*)d_in[16];
  const float* m3 = (const float*)d_in[17]; const float* v3 = (const float*)d_in[18];
  const float* w4 = (const float*)d_in[19]; const float* b4 = (const float*)d_in[20];
  const float* g4 = (const float*)d_in[21]; const float* bb4 = (const float*)d_in[22];
  const float* m4 = (const float*)d_in[23]; const float* v4 = (const float*)d_in[24];
  const float* w5 = (const float*)d_in[25]; const float* b5 = (const float*)d_in[26];
  const float* g5 = (const float*)d_in[27]; const float* bb5 = (const float*)d_in[28];
  const float* m5 = (const float*)d_in[29]; const float* v5 = (const float*)d_in[30];
  const float* wih0 = (const float*)d_in[31];
  const float* whh0 = (const float*)d_in[32];
  const float* bih0 = (const float*)d_in[33];
  const float* bhh0 = (const float*)d_in[34];
  const float* wih1 = (const float*)d_in[35];
  const float* whh1 = (const float*)d_in[36];
  const float* bih1 = (const float*)d_in[37];
  const float* bhh1 = (const float*)d_in[38];

  char* ws = (char*)d_ws;
  size_t off = 0;
  auto alloc = [&](size_t bytes) {
    size_t r = off;
    off = (off + bytes + 255) & ~(size_t)255;
    return r;
  };
  bf16_t* p1 = (bf16_t*)(ws + alloc((size_t)256 * 160 * 2));
  bf16_t* p2 = (bf16_t*)(ws + alloc((size_t)512 * 1280 * 2));
  bf16_t* p3 = (bf16_t*)(ws + alloc((size_t)256 * 2560 * 2));
  bf16_t* p4 = (bf16_t*)(ws + alloc((size_t)128 * 768 * 2));
  bf16_t* p5 = (bf16_t*)(ws + alloc((size_t)128 * 384 * 2));
  bf16_t* xp = (bf16_t*)(ws + alloc((size_t)32 * 4096 * 32 * 2));
  char* bufA = ws + alloc((size_t)32 * 4076 * 256 * 2);
  char* bufB = ws + alloc((size_t)32 * 4056 * 512 * 2);

  bf16_t* a1 = (bf16_t*)bufA;
  bf16_t* a2 = (bf16_t*)bufB;
  bf16_t* a3 = (bf16_t*)bufA;
  bf16_t* a4 = (bf16_t*)bufB;
  float*  a5 = (float*)bufA;
  float*  gi = (float*)bufB;

  hipLaunchKernelGGL(pack_w_kernel, dim3(2560, 5), dim3(256), 0, stream,
                     w1, w2, w3, w4, w5, p1, p2, p3, p4, p5);
  hipLaunchKernelGGL(pack_x_kernel, dim3(16, 32), dim3(256), 0, stream, x, xp);

  hipLaunchKernelGGL((tdnn_gemm<32, 5, 5, false>), dim3(32, 2, 32), dim3(256), 0, stream,
                     xp, p1, b1, g1, bb1, m1, v1, a1, (float*)nullptr, 4096, 4076, 256);
  hipLaunchKernelGGL((tdnn_gemm<256, 5, 5, false>), dim3(32, 4, 32), dim3(256), 0, stream,
                     a1, p2, b2, g2, bb2, m2, v2, a2, (float*)nullptr, 4076, 4056, 512);
  hipLaunchKernelGGL((tdnn_gemm<512, 5, 5, false>), dim3(32, 2, 32), dim3(256), 0, stream,
                     a2, p3, b3, g3, bb3, m3, v3, a3, (float*)nullptr, 4056, 4036, 256);
  hipLaunchKernelGGL((tdnn_gemm<256, 3, 3, false>), dim3(32, 1, 32), dim3(256), 0, stream,
                     a3, p4, b4, g4, bb4, m4, v4, a4, (float*)nullptr, 4036, 4030, 128);
  hipLaunchKernelGGL((tdnn_gemm<128, 3, 3, true>), dim3(32, 1, 32), dim3(256), 0, stream,
                     a4, p5, b5, g5, bb5, m5, v5, (bf16_t*)nullptr, a5, 4030, 4024, 128);

  hipLaunchKernelGGL(gi0_kernel, dim3(63, 32), dim3(256), 0, stream, a5, wih0, bih0, gi, 4024);
  hipLaunchKernelGGL(gru_kernel, dim3(32), dim3(64), 0, stream,
                     gi, whh0, bhh0, wih1, bih1, whh1, bhh1, (float*)d_out, 4024);
}

// Round 5
// 2107.558 us; speedup vs baseline: 1.8242x; 1.0029x over previous
//
#include <hip/hip_runtime.h>

typedef __bf16 bf16_t;
typedef __bf16 bf16x8 __attribute__((ext_vector_type(8)));
typedef float f32x4 __attribute__((ext_vector_type(4)));
typedef __fp16 f16x2 __attribute__((ext_vector_type(2)));

#define EPSBN 1e-5f

__device__ __forceinline__ void gload16(const void* g, void* l) {
  __builtin_amdgcn_global_load_lds(
      (const __attribute__((address_space(1))) void*)g,
      (__attribute__((address_space(3))) void*)l, 16, 0, 0);
}

__device__ __forceinline__ f16x2 i2h(int x) { union { int i; f16x2 h; } u; u.i = x; return u.h; }
__device__ __forceinline__ int h2i(f16x2 x) { union { int i; f16x2 h; } u; u.h = x; return u.i; }

__device__ __forceinline__ float dot2acc(f16x2 w, f16x2 h, float acc) {
#if __has_builtin(__builtin_amdgcn_fdot2)
  return __builtin_amdgcn_fdot2(w, h, acc, false);
#else
  return acc + (float)w[0] * (float)h[0] + (float)w[1] * (float)h[1];
#endif
}

// ---------------- weight packing: fp32 -> bf16 (w1 padded 20->32 ch) ----------------
__global__ __launch_bounds__(256) void pack_w_kernel(
    const float* __restrict__ w1, const float* __restrict__ w2,
    const float* __restrict__ w3, const float* __restrict__ w4,
    const float* __restrict__ w5,
    bf16_t* __restrict__ p1, bf16_t* __restrict__ p2, bf16_t* __restrict__ p3,
    bf16_t* __restrict__ p4, bf16_t* __restrict__ p5)
{
  const int idx = blockIdx.x * 256 + threadIdx.x;
  switch (blockIdx.y) {
    case 0:
      if (idx < 256 * 160) {
        int o = idx / 160, k = idx % 160, tap = k / 32, ch = k % 32;
        p1[idx] = (bf16_t)((ch < 20) ? w1[o * 100 + tap * 20 + ch] : 0.0f);
      }
      break;
    case 1: if (idx < 512 * 1280) p2[idx] = (bf16_t)w2[idx]; break;
    case 2: if (idx < 256 * 2560) p3[idx] = (bf16_t)w3[idx]; break;
    case 3: if (idx < 128 * 768)  p4[idx] = (bf16_t)w4[idx]; break;
    default: if (idx < 128 * 384) p5[idx] = (bf16_t)w5[idx]; break;
  }
}

// ---------------- x: (B,20,L) fp32 -> (B,L,32) bf16, zero-padded channels ----------------
__global__ __launch_bounds__(256) void pack_x_kernel(
    const float* __restrict__ x, bf16_t* __restrict__ xp)
{
  __shared__ __align__(16) bf16_t Ls[256 * 32];
  const int tid = threadIdx.x;
  const int b = blockIdx.y;
  const int l0 = blockIdx.x * 256;
  bf16x8 z = {};
  #pragma unroll
  for (int i = 0; i < 4; ++i) ((bf16x8*)Ls)[tid + i * 256] = z;
  __syncthreads();
  #pragma unroll
  for (int ch = 0; ch < 20; ++ch) {
    float v = x[((size_t)b * 20 + ch) * 4096 + l0 + tid];
    Ls[tid * 32 + ch] = (bf16_t)v;
  }
  __syncthreads();
  bf16x8* dst = (bf16x8*)(xp + ((size_t)b * 4096 + l0) * 32);
  #pragma unroll
  for (int i = 0; i < 4; ++i) dst[tid + i * 256] = ((bf16x8*)Ls)[tid + i * 256];
}

// ---------------- TDNN layer as MFMA GEMM over dilated taps ----------------
template <int DIN, int C, int DIL, bool OUTF32>
__global__ __launch_bounds__(256, 2) void tdnn_gemm(
    const bf16_t* __restrict__ X, const bf16_t* __restrict__ W,
    const float* __restrict__ bias, const float* __restrict__ gg,
    const float* __restrict__ bb, const float* __restrict__ mm,
    const float* __restrict__ vv,
    bf16_t* __restrict__ Yb, float* __restrict__ Yf,
    const int Lin, const int Lo, const int N)
{
  __shared__ __align__(16) bf16_t As[128 * 32];
  __shared__ __align__(16) bf16_t Bs[128 * 32];
  const int tid = threadIdx.x;
  const int wave = tid >> 6;
  const int lane = tid & 63;
  const int l0 = blockIdx.x * 128;
  const int n0 = blockIdx.y * 128;
  const int b = blockIdx.z;
  const int lm = lane & 15;
  const int quad = lane >> 4;
  const int wm = (wave >> 1) * 64;
  const int wn = (wave & 1) * 64;
  constexpr int Ktot = C * DIN;

  const int srow = wave * 32 + (lane >> 2);
  const int scol = (lane & 3) * 8;

  const int rA0 = min(l0 + srow, Lo - 1);
  const int rA1 = min(l0 + srow + 16, Lo - 1);

  const bf16_t* Xb = X + (size_t)b * Lin * DIN;
  const bf16_t* xg0 = Xb + (size_t)rA0 * DIN + scol;
  const bf16_t* xg1 = Xb + (size_t)rA1 * DIN + scol;
  const bf16_t* wg0 = W + (size_t)(n0 + srow) * Ktot + scol;
  const bf16_t* wg1 = W + (size_t)(n0 + srow + 16) * Ktot + scol;

  bf16_t* AsW = &As[(wave * 32) * 32];
  bf16_t* BsW = &Bs[(wave * 32) * 32];

  f32x4 acc[4][4];
  f32x4 zz = {};
  #pragma unroll
  for (int i = 0; i < 4; ++i)
    #pragma unroll
    for (int j = 0; j < 4; ++j) acc[i][j] = zz;

  for (int tap = 0; tap < C; ++tap) {
    const bf16_t* xa0 = xg0 + (size_t)tap * DIL * DIN;
    const bf16_t* xa1 = xg1 + (size_t)tap * DIL * DIN;
    const bf16_t* wa0 = wg0 + tap * DIN;
    const bf16_t* wa1 = wg1 + tap * DIN;
    for (int kc = 0; kc < DIN / 32; ++kc) {
      gload16(xa0 + kc * 32, AsW);
      gload16(xa1 + kc * 32, AsW + 16 * 32);
      gload16(wa0 + kc * 32, BsW);
      gload16(wa1 + kc * 32, BsW + 16 * 32);
      __syncthreads();
      bf16x8 av[4], bv[4];
      #pragma unroll
      for (int mt = 0; mt < 4; ++mt)
        av[mt] = *(const bf16x8*)&As[(wm + mt * 16 + lm) * 32 + quad * 8];
      #pragma unroll
      for (int nt = 0; nt < 4; ++nt)
        bv[nt] = *(const bf16x8*)&Bs[(wn + nt * 16 + lm) * 32 + quad * 8];
      #pragma unroll
      for (int mt = 0; mt < 4; ++mt)
        #pragma unroll
        for (int nt = 0; nt < 4; ++nt)
          acc[mt][nt] = __builtin_amdgcn_mfma_f32_16x16x32_bf16(av[mt], bv[nt], acc[mt][nt], 0, 0, 0);
      __syncthreads();
    }
  }

  #pragma unroll
  for (int nt = 0; nt < 4; ++nt) {
    const int col = n0 + wn + nt * 16 + lm;
    const float sc = gg[col] * rsqrtf(vv[col] + EPSBN);
    const float sh = bb[col] - mm[col] * sc;
    const float bi = bias[col];
    #pragma unroll
    for (int mt = 0; mt < 4; ++mt) {
      const int rbase = l0 + wm + mt * 16 + quad * 4;
      #pragma unroll
      for (int r = 0; r < 4; ++r) {
        const int row = rbase + r;
        if (row < Lo) {
          float val = fmaxf(acc[mt][nt][r] + bi, 0.0f) * sc + sh;
          const size_t oi = ((size_t)b * Lo + row) * N + col;
          if constexpr (OUTF32) Yf[oi] = val;
          else                  Yb[oi] = (bf16_t)val;
        }
      }
    }
  }
}

// ---------------- gi0 = act5 @ wih0^T + bih0, fp32; n-gate rows (32..47) pre-scaled x2 ----------------
__global__ __launch_bounds__(256, 2) void gi0_kernel(
    const float* __restrict__ A5, const float* __restrict__ wih,
    const float* __restrict__ bih, float* __restrict__ GI, const int T)
{
  __shared__ __align__(16) float Xs[64 * 132];
  __shared__ __align__(16) float Ws[48 * 132];
  const int tid = threadIdx.x;
  const int b = blockIdx.y, t0 = blockIdx.x * 64;
  for (int c = tid; c < 48 * 32; c += 256) {
    int j = c >> 5, k4 = c & 31;
    *(float4*)&Ws[j * 132 + k4 * 4] = *(const float4*)&wih[j * 128 + k4 * 4];
  }
  for (int c = tid; c < 64 * 32; c += 256) {
    int r = c >> 5, k4 = c & 31;
    int tt = min(t0 + r, T - 1);
    *(float4*)&Xs[r * 132 + k4 * 4] = *(const float4*)&A5[((size_t)b * T + tt) * 128 + k4 * 4];
  }
  __syncthreads();
  const int tl = tid >> 2, jg = tid & 3;
  float acc[12];
  #pragma unroll
  for (int i = 0; i < 12; ++i) acc[i] = 0.0f;
  for (int k = 0; k < 128; k += 4) {
    float4 xv = *(const float4*)&Xs[tl * 132 + k];
    #pragma unroll
    for (int jj = 0; jj < 12; ++jj) {
      float4 wv = *(const float4*)&Ws[(jg * 12 + jj) * 132 + k];
      acc[jj] += xv.x * wv.x + xv.y * wv.y + xv.z * wv.z + xv.w * wv.w;
    }
  }
  const int t = t0 + tl;
  if (t < T) {
    float* dst = &GI[((size_t)b * T + t) * 48 + jg * 12];
    #pragma unroll
    for (int jj = 0; jj < 12; ++jj) {
      const int row = jg * 12 + jj;
      const float s = (row >= 32) ? 2.0f : 1.0f;   // fold tanh's 2x into n-gate gi
      dst[jj] = (acc[jj] + bih[row]) * s;
    }
  }
}

// ---------------- fused 2-layer GRU: packed-f16 dot2, register-resident, barrier-free ----------------
// One wave per batch. Lane u (0..15): layer0 unit u. Lane 16+u: layer1 unit u (1 step behind).
// Weight init is UNIFORM code (pointer-select per lane) so the f16x2 arrays become
// SSA values -> VGPRs. Chain A runs over h0-broadcast for all lanes; chain B over
// h1-broadcast for all lanes (role0's chain-B result is unused garbage).
__global__ __launch_bounds__(64, 1) void gru_kernel(
    const float* __restrict__ GI,
    const float* __restrict__ whh0, const float* __restrict__ bhh0,
    const float* __restrict__ wih1, const float* __restrict__ bih1,
    const float* __restrict__ whh1, const float* __restrict__ bhh1,
    float* __restrict__ out, const int T)
{
  const int b = blockIdx.x;
  const int lane = threadIdx.x;
  const int u = lane & 15;
  const bool L1 = ((lane >> 4) & 1) != 0;        // lanes 16..31 (and 48..63, masked at store)
  const bool STORE1 = (lane >= 16 && lane < 32);

  // uniform pointer-select init: no divergent branches around the array writes
  const float* wA = L1 ? wih1 : whh0;
  const float* wB = L1 ? whh1 : whh0;            // role0: garbage chain, unused
  const float* bA = L1 ? bih1 : bhh0;
  const float* bB = L1 ? bhh1 : bhh0;            // role0: unused

  f16x2 wAr[8], wAz[8], wAn[8], wBr[8], wBz[8], wBn[8];
  #pragma unroll
  for (int m = 0; m < 8; ++m) {
    wAr[m] = __builtin_amdgcn_cvt_pkrtz(wA[u * 16 + 2 * m],              wA[u * 16 + 2 * m + 1]);
    wAz[m] = __builtin_amdgcn_cvt_pkrtz(wA[(16 + u) * 16 + 2 * m],       wA[(16 + u) * 16 + 2 * m + 1]);
    wAn[m] = __builtin_amdgcn_cvt_pkrtz(2.f * wA[(32 + u) * 16 + 2 * m], 2.f * wA[(32 + u) * 16 + 2 * m + 1]);
    wBr[m] = __builtin_amdgcn_cvt_pkrtz(wB[u * 16 + 2 * m],              wB[u * 16 + 2 * m + 1]);
    wBz[m] = __builtin_amdgcn_cvt_pkrtz(wB[(16 + u) * 16 + 2 * m],       wB[(16 + u) * 16 + 2 * m + 1]);
    wBn[m] = __builtin_amdgcn_cvt_pkrtz(2.f * wB[(32 + u) * 16 + 2 * m], 2.f * wB[(32 + u) * 16 + 2 * m + 1]);
  }
  const float iAr = bA[u], iAz = bA[16 + u], iAn = 2.f * bA[32 + u];
  const float iBr = bB[u], iBz = bB[16 + u], iBn = 2.f * bB[32 + u];

  const float* gib = GI + (size_t)b * T * 48;
  // gi register pipeline, depth 3
  float g0r = gib[u],      g0z = gib[16 + u],      g0n = gib[32 + u];
  float g1r = gib[48 + u], g1z = gib[48 + 16 + u], g1n = gib[48 + 32 + u];
  float g2r = gib[96 + u], g2z = gib[96 + 16 + u], g2n = gib[96 + 32 + u];

  float hreg = 0.f;                 // lane u: h0[u]; lane 16+u: h1[u]
  int s0[8], s1[8];
  #pragma unroll
  for (int m = 0; m < 8; ++m) { s0[m] = 0; s1[m] = 0; }

  float* outp = out + (size_t)b * T * 16 + u;

  #pragma unroll 3
  for (int i = 0; i <= T; ++i) {
    // prefetch gi for step i+3
    const int tp = min(i + 3, T - 1);
    const float* gp = gib + (size_t)tp * 48 + u;
    const float g3r = gp[0], g3z = gp[16], g3n = gp[32];

    // chain A over s0 (h0-broadcast), chain B over s1 (h1-broadcast)
    float cAr = iAr, cAz = iAz, cAn = iAn;
    float cBr = iBr, cBz = iBz, cBn = iBn;
    #pragma unroll
    for (int m = 0; m < 8; ++m) {
      const f16x2 a = i2h(s0[m]), bb_ = i2h(s1[m]);
      cAr = dot2acc(wAr[m], a, cAr);
      cAz = dot2acc(wAz[m], a, cAz);
      cAn = dot2acc(wAn[m], a, cAn);
      cBr = dot2acc(wBr[m], bb_, cBr);
      cBz = dot2acc(wBz[m], bb_, cBz);
      cBn = dot2acc(wBn[m], bb_, cBn);
    }

    const float aIr = L1 ? cAr : g0r;  const float aRr = L1 ? cBr : cAr;
    const float aIz = L1 ? cAz : g0z;  const float aRz = L1 ? cBz : cAz;
    const float aIn = L1 ? cAn : g0n;  const float aRn = L1 ? cBn : cAn;

    const float r = 1.0f / (1.0f + __expf(-(aIr + aRr)));
    const float z = 1.0f / (1.0f + __expf(-(aIz + aRz)));
    // n-gate: weights/bias/gi pre-scaled by 2 -> e = exp(2*(in + r*hn))
    const float e = __expf(aIn + r * aRn);
    const float n = 1.0f - 2.0f / (e + 1.0f);
    float hnew = n + z * (hreg - n);

    if (i == 0 && L1) hnew = 0.f;    // layer-1 pipeline warm-up
    hreg = hnew;

    if (i > 0 && STORE1)
      outp[(size_t)(i - 1) * 16] = hnew;

    // neighbor swap via DPP (quad_perm [1,0,3,2] = 0xB1), then pack f16 pairs
    const int hi = __float_as_int(hreg);
#if __has_builtin(__builtin_amdgcn_mov_dpp)
    const float hp = __int_as_float(__builtin_amdgcn_mov_dpp(hi, 0xB1, 0xF, 0xF, true));
#else
    const float hp = __shfl_xor(hreg, 1);
#endif
    const int pkE = h2i(__builtin_amdgcn_cvt_pkrtz(hreg, hp));
    const int pkO = h2i(__builtin_amdgcn_cvt_pkrtz(hp, hreg));
    const int pki = (lane & 1) ? pkO : pkE;
    #pragma unroll
    for (int m = 0; m < 8; ++m) {
      s0[m] = __builtin_amdgcn_readlane(pki, 2 * m);
      s1[m] = __builtin_amdgcn_readlane(pki, 16 + 2 * m);
    }

    g0r = g1r; g0z = g1z; g0n = g1n;
    g1r = g2r; g1z = g2z; g1n = g2n;
    g2r = g3r; g2z = g3z; g2n = g3n;
  }
}

extern "C" void kernel_launch(void* const* d_in, const int* in_sizes, int n_in,
                              void* d_out, int out_size, void* d_ws, size_t ws_size,
                              hipStream_t stream) {
  (void)in_sizes; (void)n_in; (void)out_size; (void)ws_size;
  const float* x = (const float*)d_in[0];
  const float* w1 = (const float*)d_in[1];  const float* b1 = (const float*)d_in[2];
  const float* g1 = (const float*)d_in[3];  const float* bb1 = (const float*)d_in[4];
  const float* m1 = (const float*)d_in[5];  const float* v1 = (const float*)d_in[6];
  const float* w2 = (const float*)d_in[7];  const float* b2 = (const float*)d_in[8];
  const float* g2 = (const float*)d_in[9];  const float* bb2 = (const float*)d_in[10];
  const float* m2 = (const float*)d_in[11]; const float* v2 = (const float*)d_in[12];
  const float* w3 = (const float*)d_in[13]; const float* b3 = (const float*)d_in[14];
  const float* g3 = (const float*)d_in[15]; const float* bb3 = (const float*)d_in[16];
  const float* m3 = (const float*)d_in[17]; const float* v3 = (const float*)d_in[18];
  const float* w4 = (const float*)d_in[19]; const float* b4 = (const float*)d_in[20];
  const float* g4 = (const float*)d_in[21]; const float* bb4 = (const float*)d_in[22];
  const float* m4 = (const float*)d_in[23]; const float* v4 = (const float*)d_in[24];
  const float* w5 = (const float*)d_in[25]; const float* b5 = (const float*)d_in[26];
  const float* g5 = (const float*)d_in[27]; const float* bb5 = (const float*)d_in[28];
  const float* m5 = (const float*)d_in[29]; const float* v5 = (const float*)d_in[30];
  const float* wih0 = (const float*)d_in[31];
  const float* whh0 = (const float*)d_in[32];
  const float* bih0 = (const float*)d_in[33];
  const float* bhh0 = (const float*)d_in[34];
  const float* wih1 = (const float*)d_in[35];
  const float* whh1 = (const float*)d_in[36];
  const float* bih1 = (const float*)d_in[37];
  const float* bhh1 = (const float*)d_in[38];

  char* ws = (char*)d_ws;
  size_t off = 0;
  auto alloc = [&](size_t bytes) {
    size_t r = off;
    off = (off + bytes + 255) & ~(size_t)255;
    return r;
  };
  bf16_t* p1 = (bf16_t*)(ws + alloc((size_t)256 * 160 * 2));
  bf16_t* p2 = (bf16_t*)(ws + alloc((size_t)512 * 1280 * 2));
  bf16_t* p3 = (bf16_t*)(ws + alloc((size_t)256 * 2560 * 2));
  bf16_t* p4 = (bf16_t*)(ws + alloc((size_t)128 * 768 * 2));
  bf16_t* p5 = (bf16_t*)(ws + alloc((size_t)128 * 384 * 2));
  bf16_t* xp = (bf16_t*)(ws + alloc((size_t)32 * 4096 * 32 * 2));
  char* bufA = ws + alloc((size_t)32 * 4076 * 256 * 2);
  char* bufB = ws + alloc((size_t)32 * 4056 * 512 * 2);

  bf16_t* a1 = (bf16_t*)bufA;
  bf16_t* a2 = (bf16_t*)bufB;
  bf16_t* a3 = (bf16_t*)bufA;
  bf16_t* a4 = (bf16_t*)bufB;
  float*  a5 = (float*)bufA;
  float*  gi = (float*)bufB;

  hipLaunchKernelGGL(pack_w_kernel, dim3(2560, 5), dim3(256), 0, stream,
                     w1, w2, w3, w4, w5, p1, p2, p3, p4, p5);
  hipLaunchKernelGGL(pack_x_kernel, dim3(16, 32), dim3(256), 0, stream, x, xp);

  hipLaunchKernelGGL((tdnn_gemm<32, 5, 5, false>), dim3(32, 2, 32), dim3(256), 0, stream,
                     xp, p1, b1, g1, bb1, m1, v1, a1, (float*)nullptr, 4096, 4076, 256);
  hipLaunchKernelGGL((tdnn_gemm<256, 5, 5, false>), dim3(32, 4, 32), dim3(256), 0, stream,
                     a1, p2, b2, g2, bb2, m2, v2, a2, (float*)nullptr, 4076, 4056, 512);
  hipLaunchKernelGGL((tdnn_gemm<512, 5, 5, false>), dim3(32, 2, 32), dim3(256), 0, stream,
                     a2, p3, b3, g3, bb3, m3, v3, a3, (float*)nullptr, 4056, 4036, 256);
  hipLaunchKernelGGL((tdnn_gemm<256, 3, 3, false>), dim3(32, 1, 32), dim3(256), 0, stream,
                     a3, p4, b4, g4, bb4, m4, v4, a4, (float*)nullptr, 4036, 4030, 128);
  hipLaunchKernelGGL((tdnn_gemm<128, 3, 3, true>), dim3(32, 1, 32), dim3(256), 0, stream,
                     a4, p5, b5, g5, bb5, m5, v5, (bf16_t*)nullptr, a5, 4030, 4024, 128);

  hipLaunchKernelGGL(gi0_kernel, dim3(63, 32), dim3(256), 0, stream, a5, wih0, bih0, gi, 4024);
  hipLaunchKernelGGL(gru_kernel, dim3(32), dim3(64), 0, stream,
                     gi, whh0, bhh0, wih1, bih1, whh1, bhh1, (float*)d_out, 4024);
}